// Round 7
// baseline (630.942 us; speedup 1.0000x reference)
//
#include <hip/hip_runtime.h>
#include <math.h>

#define DIM   96
#define C4    384
#define STYLE 128
#define LAT   8
#define KK    7
#define BB    2
#define SPD   48
#define SP3   (SPD*SPD*SPD)   /* 110592 */
#define EPSV  1e-6f

/* ---- kconv tile geometry (R11 layout, R13 dot2 inner loop) ----
   R12 post-mortem: kconv 276 us, VALUBusy 71%, Occ 57% -> VALU-issue
   bound. R13: v_dot2_f32_bf16 (2 bf16 MAC + f32 accum per instr) on the
   packed-bf16 LDS dwords: even j uses aligned dwords, odd j uses 6
   v_alignbit-shifted dwords/row (replaces the 14 unpack ops). Weights
   pre-packed in kw as [49] rows x {pk01,pk23,pk45,w6_f32} -> uniform
   s_load_dwordx4, no per-thread weight prep. Per-row VALU 126 -> 78. */
#define XTS_E 30              /* bf16 elems per row slot (dword stride 15 odd) */
#define YB    2
#define YSPAN 16              /* 8 ty * YB */
#define ZSPAN 8
#define XSPAN 24              /* 3 tx * 8 */
#define YROWS 22              /* YSPAN+6 staged rows */
#define YROWP 23              /* row-slot stride per z-plane */
#define ZPL   14              /* ZSPAN+6 planes */

/* workspace layout in floats (WS_WDW now holds packed dw weights:
   per (b,c) 49 rows x 4 dwords = 196 < 343 alloc -> offsets unchanged) */
#define WS_Z    0                               /* 48: [which3][b2][l8] */
#define WS_WDW  64                              /* packed dw weights */
#define WS_BDW  (WS_WDW + BB*DIM*343)           /* 192, [b][c] fp32 */
#define WS_W1   (WS_BDW + BB*DIM)               /* W1b bf16 [b][384][96] */
#define WS_B1   (WS_W1 + BB*C4*DIM)             /* 768 fp32, [b][o4] */
#define WS_W2T  (WS_B1 + BB*C4)                 /* W2b bf16 [b][96][384] */
#define WS_B2   (WS_W2T + BB*C4*DIM)            /* 192 fp32, [b][o] */
#define WS_H    (WS_B2 + BB*DIM)                /* 2*96*110592 fp32 */

typedef __attribute__((ext_vector_type(8))) __bf16 bf16x8;
typedef __attribute__((ext_vector_type(4))) __bf16 bf16x4;
typedef __attribute__((ext_vector_type(4))) float  f32x4;

#define DOT2(accv, av, bv) \
    asm("v_dot2_f32_bf16 %0, %1, %2, %0" : "+v"(accv) : "v"(av), "v"(bv))

/* ---------- kernel 1: style -> latent z for the three hyper nets ---------- */
__global__ __launch_bounds__(64) void kz(const float* __restrict__ s,
                                         const float* __restrict__ dwfw, const float* __restrict__ dwfb,
                                         const float* __restrict__ p1fw, const float* __restrict__ p1fb,
                                         const float* __restrict__ p2fw, const float* __restrict__ p2fb,
                                         float* __restrict__ ws) {
    int t = threadIdx.x;
    if (t >= 48) return;
    int which = t >> 4;      /* 0=dw, 1=pw1, 2=pw2 */
    int b = (t >> 3) & 1;
    int l = t & 7;
    const float* fw = (which == 0) ? dwfw : (which == 1) ? p1fw : p2fw;
    const float* fb = (which == 0) ? dwfb : (which == 1) ? p1fb : p2fb;
    float acc = fb[l];
    for (int k = 0; k < STYLE; ++k) acc += s[b*STYLE + k] * fw[l*STYLE + k];
    ws[WS_Z + which*16 + b*8 + l] = acc;
}

/* ---------- kernel 2: latent z -> per-batch conv weights/biases ----------
   R13: dw weights written PACKED for the dot2 kconv: per (b,c) 49 rows of
   {cvt_pk(w0,w1), cvt_pk(w2,w3), cvt_pk(w4,w5), w6 fp32}. */
__global__ __launch_bounds__(256) void kw(const float* __restrict__ dwb,  const float* __restrict__ dwbb,
                                          const float* __restrict__ p1b,  const float* __restrict__ p1bb,
                                          const float* __restrict__ p2b,  const float* __restrict__ p2bb,
                                          float* __restrict__ ws) {
    const int n0 = BB*DIM*49*4;         /* packed w_dw slots */
    const int n1 = n0 + BB*DIM;         /* b_dw  */
    const int n2 = n1 + BB*C4*DIM;      /* w1    */
    const int n3 = n2 + BB*C4;          /* b1    */
    const int n4 = n3 + BB*C4*DIM;      /* w2    */
    const int n5 = n4 + BB*DIM;         /* b2    */
    int i = blockIdx.x * blockDim.x + threadIdx.x;
    if (i >= n5) return;
    const float* zdw = ws + WS_Z;
    const float* z1  = ws + WS_Z + 16;
    const float* z2  = ws + WS_Z + 32;
    if (i < n0) {
        int b = i / (DIM*196); int r = i % (DIM*196); int c = r / 196; int s = r % 196;
        int row = s >> 2;               /* dz*7+dy, 0..48 */
        int slot = s & 3;               /* 0..3 */
        const float* z = zdw + b*8;
        const float* bank = dwb + ((size_t)(c*343 + row*7))*LAT;
        if (slot < 3) {
            float a0 = 0.f, a1 = 0.f;
            #pragma unroll
            for (int l = 0; l < LAT; ++l) {
                a0 += bank[(2*slot)*LAT + l]*z[l];
                a1 += bank[(2*slot+1)*LAT + l]*z[l];
            }
            uint32_t p;
            asm("v_cvt_pk_bf16_f32 %0, %1, %2" : "=v"(p) : "v"(a0), "v"(a1));
            ((uint32_t*)(ws + WS_WDW))[(b*DIM + c)*196 + s] = p;
        } else {
            float a = 0.f;
            #pragma unroll
            for (int l = 0; l < LAT; ++l) a += bank[6*LAT + l]*z[l];
            ws[WS_WDW + (b*DIM + c)*196 + s] = a;
        }
    } else if (i < n1) {
        int j = i - n0; int b = j / DIM; int c = j % DIM;
        const float* z = zdw + b*8;
        float a = 0.f;
        #pragma unroll
        for (int l = 0; l < LAT; ++l) a += dwbb[c*LAT + l]*z[l];
        ws[WS_BDW + j] = a;
    } else if (i < n2) {
        int j = i - n1; int b = j / (C4*DIM); int r = j % (C4*DIM); int o = r / DIM; int c = r % DIM;
        const float* z = z1 + b*8;
        const float* bank = p1b + ((size_t)(o*DIM + c))*LAT;
        float a = 0.f;
        #pragma unroll
        for (int l = 0; l < LAT; ++l) a += bank[l]*z[l];
        ((__bf16*)(ws + WS_W1))[j] = (__bf16)a;          /* [b][o][c] */
    } else if (i < n3) {
        int j = i - n2; int b = j / C4; int o = j % C4;
        const float* z = z1 + b*8;
        float a = 0.f;
        #pragma unroll
        for (int l = 0; l < LAT; ++l) a += p1bb[o*LAT + l]*z[l];
        ws[WS_B1 + j] = a;
    } else if (i < n4) {
        int j = i - n3; int b = j / (C4*DIM); int r = j % (C4*DIM); int o = r / C4; int c4 = r % C4;
        const float* z = z2 + b*8;
        const float* bank = p2b + ((size_t)(o*C4 + c4))*LAT;
        float a = 0.f;
        #pragma unroll
        for (int l = 0; l < LAT; ++l) a += bank[l]*z[l];
        ((__bf16*)(ws + WS_W2T))[j] = (__bf16)a;         /* [b][o][c4] */
    } else {
        int j = i - n4; int b = j / DIM; int o = j % DIM;
        const float* z = z2 + b*8;
        float a = 0.f;
        #pragma unroll
        for (int l = 0; l < LAT; ++l) a += p2bb[o*LAT + l]*z[l];
        ws[WS_B2 + j] = a;
    }
}

/* ---------- kernel 3: depthwise 7x7x7 conv (+bias) -> h in ws ----------
   R13: dot2 inner loop. Staging / LDS layout / bank math byte-identical
   to R11 (verified). Even j: 3 dot2 on aligned dwords + fp32 tail fma.
   Odd j: 3 dot2 on alignbit-shifted dwords + fp32 tail fma. */
__global__ __launch_bounds__(192, 4) void kconv(const float* __restrict__ x, float* __restrict__ ws) {
    __shared__ __bf16 xt[ZPL*YROWP*XTS_E];             /* 14*23*30*2 = 19320 B */
    int tid = threadIdx.x;
    int bx = blockIdx.x;                               /* 36 = 6z * 3y * 2x */
    int zt = bx / 6;
    int rt = bx % 6; int yt = rt >> 1; int xti = rt & 1;
    int c = blockIdx.y, b = blockIdx.z;
    int z0 = zt*ZSPAN, y0 = yt*YSPAN, x0 = xti*XSPAN;

    const float* xsrc = x + ((size_t)(b*DIM + c))*SP3;
    for (int i = tid; i < ZPL*YROWS*XTS_E; i += 192) { /* 9240 elems */
        int iz = i / (YROWS*XTS_E); int r = i % (YROWS*XTS_E);
        int iy = r / XTS_E; int ix = r % XTS_E;
        int gz = z0 - 3 + iz, gy = y0 - 3 + iy, gx = x0 + ix - 3;
        float v = 0.f;
        if ((unsigned)gz < 48u && (unsigned)gy < 48u && (unsigned)gx < 48u)
            v = xsrc[(gz*SPD + gy)*SPD + gx];
        xt[(iz*YROWP + iy)*XTS_E + ix] = (__bf16)v;
    }
    __syncthreads();

    int tz = tid / 24; int rem = tid % 24; int ty = rem / 3; int tx = rem % 3;
    int xb = tx*8;
    float acc[YB][8];
    #pragma unroll
    for (int yl = 0; yl < YB; ++yl)
        #pragma unroll
        for (int j = 0; j < 8; ++j) acc[yl][j] = 0.f;

    const float4* wp4 = (const float4*)(ws + WS_WDW) + (size_t)(b*DIM + c)*49;

    #pragma unroll 1
    for (int dz = 0; dz < 7; ++dz) {
        /* 7 packed weight rows for this dz: uniform s_load_dwordx4 */
        float4 wq[7];
        #pragma unroll
        for (int dy = 0; dy < 7; ++dy) wq[dy] = wp4[dz*7 + dy];

        const int zr = (tz + dz)*YROWP + ty*YB;
        #pragma unroll
        for (int r = 0; r < YB + 6; ++r) {
            const uint32_t* rowp = (const uint32_t*)&xt[(zr + r)*XTS_E + xb];
            uint32_t dwv[7];
            #pragma unroll
            for (int k = 0; k < 7; ++k) dwv[k] = rowp[k];
            uint32_t sh[6];
            #pragma unroll
            for (int k = 0; k < 6; ++k)
                asm("v_alignbit_b32 %0, %1, %2, 16"
                    : "=v"(sh[k]) : "v"(dwv[k+1]), "v"(dwv[k]));
            float tlo[4], thi[4];
            #pragma unroll
            for (int m = 0; m < 4; ++m) {
                tlo[m] = __uint_as_float(dwv[3+m] << 16);
                thi[m] = __uint_as_float(dwv[3+m] & 0xffff0000u);
            }
            #pragma unroll
            for (int yl = 0; yl < YB; ++yl) {
                const int dy = r - yl;
                if (dy >= 0 && dy < 7) {
                    const uint32_t w01 = __float_as_uint(wq[dy].x);
                    const uint32_t w23 = __float_as_uint(wq[dy].y);
                    const uint32_t w45 = __float_as_uint(wq[dy].z);
                    const float    w6  = wq[dy].w;
                    #pragma unroll
                    for (int m = 0; m < 4; ++m) {      /* even j = 2m */
                        float a = acc[yl][2*m];
                        DOT2(a, w01, dwv[m]);
                        DOT2(a, w23, dwv[m+1]);
                        DOT2(a, w45, dwv[m+2]);
                        a = fmaf(w6, tlo[m], a);
                        acc[yl][2*m] = a;
                    }
                    #pragma unroll
                    for (int m = 0; m < 4; ++m) {      /* odd j = 2m+1 */
                        float a = acc[yl][2*m+1];
                        DOT2(a, w01, sh[m]);
                        DOT2(a, w23, sh[m+1]);
                        DOT2(a, w45, sh[m+2]);
                        a = fmaf(w6, thi[m], a);
                        acc[yl][2*m+1] = a;
                    }
                }
            }
        }
    }

    float bias = ws[WS_BDW + b*DIM + c];
    #pragma unroll
    for (int yl = 0; yl < YB; ++yl) {
        float* hdst = ws + WS_H + ((size_t)(b*DIM + c))*SP3
                    + (((z0+tz)*SPD + (y0 + ty*YB + yl))*SPD + (x0 + xb));
        #pragma unroll
        for (int j = 0; j < 8; ++j) hdst[j] = acc[yl][j] + bias;
    }
}

/* ---------- kernel 4: LN + pw1 + GELU + pw2 + residual ----------
   R12 chunked-G version (verified): Gq reused across 4 chunks of 96
   o-values; GEMM2 accumulators in registers; LDS 28672 B. */
__global__ __launch_bounds__(256) void kpw(const float* __restrict__ x,
                                           const float* __restrict__ lnw, const float* __restrict__ lnb,
                                           const float* __restrict__ gamma,
                                           float* __restrict__ out, const float* __restrict__ ws) {
    __shared__ __align__(16) __bf16 Hn[64][104];   /* 13312 B */
    __shared__ __align__(16) __bf16 Gq[64][104];   /* 13312 B (96 cols used) */
    __shared__ float2 redbuf[256];                 /*  2048 B -> total 28672 */

    const int tid  = threadIdx.x;
    const int lane = tid & 63;
    const int w    = tid >> 6;
    const int b    = blockIdx.y;
    const int sp0  = blockIdx.x * 64;

    /* ---- Phase A: load h, LayerNorm, write bf16 Hn ---- */
    {
        const float* hp = ws + WS_H + (size_t)b*DIM*SP3 + (size_t)(w*24)*SP3 + sp0 + lane;
        float hv[24]; float s = 0.f, q = 0.f;
        #pragma unroll
        for (int i = 0; i < 24; ++i) {
            float v = hp[(size_t)i*SP3];
            hv[i] = v; s += v; q += v*v;
        }
        redbuf[w*64 + lane] = make_float2(s, q);
        __syncthreads();
        float2 r0 = redbuf[lane], r1 = redbuf[64+lane], r2 = redbuf[128+lane], r3 = redbuf[192+lane];
        float st = (r0.x+r1.x) + (r2.x+r3.x);
        float qt = (r0.y+r1.y) + (r2.y+r3.y);
        float mean = st * (1.f/96.f);
        float var  = qt * (1.f/96.f) - mean*mean;
        float rstd = rsqrtf(fmaxf(var, 0.f) + EPSV);
        #pragma unroll
        for (int i = 0; i < 24; ++i) {
            float nv = (hv[i] - mean)*rstd*lnw[w*24+i] + lnb[w*24+i];
            Hn[lane][w*24 + i] = (__bf16)nv;
        }
    }
    __syncthreads();

    const __bf16* W1b = (const __bf16*)(ws + WS_W1)  + (size_t)b*C4*DIM;
    const __bf16* W2b = (const __bf16*)(ws + WS_W2T) + (size_t)b*DIM*C4;
    const float*  b1  = ws + WS_B1 + b*C4;
    const float*  b2  = ws + WS_B2 + b*DIM;

    const int l16  = lane & 15;
    const int quad = lane >> 4;

    const __bf16* bp = &Hn[w*16 + l16][quad*8];
    bf16x8 Bf0 = *(const bf16x8*)(bp);
    bf16x8 Bf1 = *(const bf16x8*)(bp + 32);
    bf16x8 Bf2 = *(const bf16x8*)(bp + 64);

    float acc2[6][4];
    #pragma unroll
    for (int m = 0; m < 6; ++m)
        #pragma unroll
        for (int r = 0; r < 4; ++r) acc2[m][r] = 0.f;

    #pragma unroll 1
    for (int q = 0; q < 4; ++q) {
        #pragma unroll 1
        for (int mtl = 0; mtl < 6; ++mtl) {
            const __bf16* ap = W1b + (size_t)((q*6 + mtl)*16 + l16)*DIM + quad*8;
            bf16x8 a0 = *(const bf16x8*)(ap);
            bf16x8 a1 = *(const bf16x8*)(ap + 32);
            bf16x8 a2 = *(const bf16x8*)(ap + 64);
            f32x4 acc = {0.f, 0.f, 0.f, 0.f};
            acc = __builtin_amdgcn_mfma_f32_16x16x32_bf16(a0, Bf0, acc, 0, 0, 0);
            acc = __builtin_amdgcn_mfma_f32_16x16x32_bf16(a1, Bf1, acc, 0, 0, 0);
            acc = __builtin_amdgcn_mfma_f32_16x16x32_bf16(a2, Bf2, acc, 0, 0, 0);
            int og = (q*6 + mtl)*16 + quad*4;
            int ol = mtl*16 + quad*4;
            bf16x4 gv;
            #pragma unroll
            for (int r = 0; r < 4; ++r) {
                float t = acc[r] + b1[og + r];
                float g = 0.5f*t*(1.f + erff(t*0.70710678f));
                gv[r] = (__bf16)g;
            }
            *(bf16x4*)&Gq[w*16 + l16][ol] = gv;
        }
        __syncthreads();

        #pragma unroll 1
        for (int ksl = 0; ksl < 3; ++ksl) {
            bf16x8 Bg = *(const bf16x8*)&Gq[w*16 + l16][ksl*32 + quad*8];
            const int kbase = q*96 + ksl*32 + quad*8;
            #pragma unroll
            for (int mt2 = 0; mt2 < 6; ++mt2) {
                const __bf16* ap2 = W2b + (size_t)(mt2*16 + l16)*C4 + kbase;
                bf16x8 a = *(const bf16x8*)(ap2);
                f32x4 cacc = {acc2[mt2][0], acc2[mt2][1], acc2[mt2][2], acc2[mt2][3]};
                cacc = __builtin_amdgcn_mfma_f32_16x16x32_bf16(a, Bg, cacc, 0, 0, 0);
                acc2[mt2][0] = cacc[0]; acc2[mt2][1] = cacc[1];
                acc2[mt2][2] = cacc[2]; acc2[mt2][3] = cacc[3];
            }
        }
        __syncthreads();
    }

    const int j = w*16 + l16;
    const size_t base = (size_t)b*DIM*SP3 + sp0 + j;
    #pragma unroll
    for (int mt2 = 0; mt2 < 6; ++mt2) {
        int obase = mt2*16 + quad*4;
        #pragma unroll
        for (int r = 0; r < 4; ++r) {
            int o = obase + r;
            size_t idx = base + (size_t)o*SP3;
            float y = acc2[mt2][r] + b2[o];
            out[idx] = x[idx] + gamma[o]*y;
        }
    }
}

extern "C" void kernel_launch(void* const* d_in, const int* in_sizes, int n_in,
                              void* d_out, int out_size, void* d_ws, size_t ws_size,
                              hipStream_t stream) {
    const float* x      = (const float*)d_in[0];
    const float* s      = (const float*)d_in[1];
    const float* lnw    = (const float*)d_in[2];
    const float* lnb    = (const float*)d_in[3];
    const float* gamma  = (const float*)d_in[4];
    const float* dwfw   = (const float*)d_in[5];
    const float* dwfb   = (const float*)d_in[6];
    const float* dwbank = (const float*)d_in[7];
    const float* dwbb   = (const float*)d_in[8];
    const float* p1fw   = (const float*)d_in[9];
    const float* p1fb   = (const float*)d_in[10];
    const float* p1bank = (const float*)d_in[11];
    const float* p1bb   = (const float*)d_in[12];
    const float* p2fw   = (const float*)d_in[13];
    const float* p2fb   = (const float*)d_in[14];
    const float* p2bank = (const float*)d_in[15];
    const float* p2bb   = (const float*)d_in[16];
    float* ws  = (float*)d_ws;
    float* out = (float*)d_out;

    kz<<<1, 64, 0, stream>>>(s, dwfw, dwfb, p1fw, p1fb, p2fw, p2fb, ws);
    const int totW = BB*DIM*49*4 + BB*DIM + BB*C4*DIM + BB*C4 + BB*C4*DIM + BB*DIM;
    kw<<<(totW + 255)/256, 256, 0, stream>>>(dwbank, dwbb, p1bank, p1bb, p2bank, p2bb, ws);
    kconv<<<dim3(36, DIM, BB), 192, 0, stream>>>(x, ws);
    kpw<<<dim3(SP3/64, BB), 256, 0, stream>>>(x, lnw, lnb, gamma, out, ws);
}

// Round 8
// 622.315 us; speedup vs baseline: 1.0139x; 1.0139x over previous
//
#include <hip/hip_runtime.h>
#include <math.h>

#define DIM   96
#define C4    384
#define STYLE 128
#define LAT   8
#define KK    7
#define BB    2
#define SPD   48
#define SP3   (SPD*SPD*SPD)   /* 110592 */
#define EPSV  1e-6f

/* ---- kconv tile geometry (R13, kept verbatim: measured best 264 us) ----
   R13 post-mortem note: v_dot2_f32_bf16 is ~half-rate vs v_fma_f32 on
   gfx950 (VALU-busy time unchanged 196->199 us despite 0.62x ops). kconv
   is at its VALU wall ~200 us busy; MFMA-Toeplitz alternative is LDS-
   fragment-feed bound (~190 us) -> no win. Leave kconv as-is. */
#define XTS_E 30              /* bf16 elems per row slot (dword stride 15 odd) */
#define YB    2
#define YSPAN 16              /* 8 ty * YB */
#define ZSPAN 8
#define XSPAN 24              /* 3 tx * 8 */
#define YROWS 22              /* YSPAN+6 staged rows */
#define YROWP 23              /* row-slot stride per z-plane */
#define ZPL   14              /* ZSPAN+6 planes */

/* workspace layout in floats */
#define WS_Z    0                               /* 48: [which3][b2][l8] */
#define WS_WDW  64                              /* packed dw weights */
#define WS_BDW  (WS_WDW + BB*DIM*343)           /* 192, [b][c] fp32 */
#define WS_W1   (WS_BDW + BB*DIM)               /* W1b bf16 [b][384][96] */
#define WS_B1   (WS_W1 + BB*C4*DIM)             /* 768 fp32, [b][o4] */
#define WS_W2T  (WS_B1 + BB*C4)                 /* W2b bf16 [b][96][384] */
#define WS_B2   (WS_W2T + BB*C4*DIM)            /* 192 fp32, [b][o] */
#define WS_H    (WS_B2 + BB*DIM)                /* 2*96*110592 fp32 */

typedef __attribute__((ext_vector_type(8))) __bf16 bf16x8;
typedef __attribute__((ext_vector_type(4))) __bf16 bf16x4;
typedef __attribute__((ext_vector_type(4))) float  f32x4;

#define DOT2(accv, av, bv) \
    asm("v_dot2_f32_bf16 %0, %1, %2, %0" : "+v"(accv) : "v"(av), "v"(bv))

/* ---------- kernel 1: style -> latent z for the three hyper nets ---------- */
__global__ __launch_bounds__(64) void kz(const float* __restrict__ s,
                                         const float* __restrict__ dwfw, const float* __restrict__ dwfb,
                                         const float* __restrict__ p1fw, const float* __restrict__ p1fb,
                                         const float* __restrict__ p2fw, const float* __restrict__ p2fb,
                                         float* __restrict__ ws) {
    int t = threadIdx.x;
    if (t >= 48) return;
    int which = t >> 4;      /* 0=dw, 1=pw1, 2=pw2 */
    int b = (t >> 3) & 1;
    int l = t & 7;
    const float* fw = (which == 0) ? dwfw : (which == 1) ? p1fw : p2fw;
    const float* fb = (which == 0) ? dwfb : (which == 1) ? p1fb : p2fb;
    float acc = fb[l];
    for (int k = 0; k < STYLE; ++k) acc += s[b*STYLE + k] * fw[l*STYLE + k];
    ws[WS_Z + which*16 + b*8 + l] = acc;
}

/* ---------- kernel 2: latent z -> per-batch conv weights/biases ----------
   dw weights PACKED for the dot2 kconv: per (b,c) 49 rows of
   {cvt_pk(w0,w1), cvt_pk(w2,w3), cvt_pk(w4,w5), w6 fp32}. */
__global__ __launch_bounds__(256) void kw(const float* __restrict__ dwb,  const float* __restrict__ dwbb,
                                          const float* __restrict__ p1b,  const float* __restrict__ p1bb,
                                          const float* __restrict__ p2b,  const float* __restrict__ p2bb,
                                          float* __restrict__ ws) {
    const int n0 = BB*DIM*49*4;         /* packed w_dw slots */
    const int n1 = n0 + BB*DIM;         /* b_dw  */
    const int n2 = n1 + BB*C4*DIM;      /* w1    */
    const int n3 = n2 + BB*C4;          /* b1    */
    const int n4 = n3 + BB*C4*DIM;      /* w2    */
    const int n5 = n4 + BB*DIM;         /* b2    */
    int i = blockIdx.x * blockDim.x + threadIdx.x;
    if (i >= n5) return;
    const float* zdw = ws + WS_Z;
    const float* z1  = ws + WS_Z + 16;
    const float* z2  = ws + WS_Z + 32;
    if (i < n0) {
        int b = i / (DIM*196); int r = i % (DIM*196); int c = r / 196; int s = r % 196;
        int row = s >> 2;               /* dz*7+dy, 0..48 */
        int slot = s & 3;               /* 0..3 */
        const float* z = zdw + b*8;
        const float* bank = dwb + ((size_t)(c*343 + row*7))*LAT;
        if (slot < 3) {
            float a0 = 0.f, a1 = 0.f;
            #pragma unroll
            for (int l = 0; l < LAT; ++l) {
                a0 += bank[(2*slot)*LAT + l]*z[l];
                a1 += bank[(2*slot+1)*LAT + l]*z[l];
            }
            uint32_t p;
            asm("v_cvt_pk_bf16_f32 %0, %1, %2" : "=v"(p) : "v"(a0), "v"(a1));
            ((uint32_t*)(ws + WS_WDW))[(b*DIM + c)*196 + s] = p;
        } else {
            float a = 0.f;
            #pragma unroll
            for (int l = 0; l < LAT; ++l) a += bank[6*LAT + l]*z[l];
            ws[WS_WDW + (b*DIM + c)*196 + s] = a;
        }
    } else if (i < n1) {
        int j = i - n0; int b = j / DIM; int c = j % DIM;
        const float* z = zdw + b*8;
        float a = 0.f;
        #pragma unroll
        for (int l = 0; l < LAT; ++l) a += dwbb[c*LAT + l]*z[l];
        ws[WS_BDW + j] = a;
    } else if (i < n2) {
        int j = i - n1; int b = j / (C4*DIM); int r = j % (C4*DIM); int o = r / DIM; int c = r % DIM;
        const float* z = z1 + b*8;
        const float* bank = p1b + ((size_t)(o*DIM + c))*LAT;
        float a = 0.f;
        #pragma unroll
        for (int l = 0; l < LAT; ++l) a += bank[l]*z[l];
        ((__bf16*)(ws + WS_W1))[j] = (__bf16)a;          /* [b][o][c] */
    } else if (i < n3) {
        int j = i - n2; int b = j / C4; int o = j % C4;
        const float* z = z1 + b*8;
        float a = 0.f;
        #pragma unroll
        for (int l = 0; l < LAT; ++l) a += p1bb[o*LAT + l]*z[l];
        ws[WS_B1 + j] = a;
    } else if (i < n4) {
        int j = i - n3; int b = j / (C4*DIM); int r = j % (C4*DIM); int o = r / C4; int c4 = r % C4;
        const float* z = z2 + b*8;
        const float* bank = p2b + ((size_t)(o*C4 + c4))*LAT;
        float a = 0.f;
        #pragma unroll
        for (int l = 0; l < LAT; ++l) a += bank[l]*z[l];
        ((__bf16*)(ws + WS_W2T))[j] = (__bf16)a;         /* [b][o][c4] */
    } else {
        int j = i - n4; int b = j / DIM; int o = j % DIM;
        const float* z = z2 + b*8;
        float a = 0.f;
        #pragma unroll
        for (int l = 0; l < LAT; ++l) a += p2bb[o*LAT + l]*z[l];
        ws[WS_B2 + j] = a;
    }
}

/* ---------- kernel 3: depthwise 7x7x7 conv (+bias) -> h in ws ----------
   R13 (verified, 264 us): dot2 inner loop on packed-bf16 LDS dwords. */
__global__ __launch_bounds__(192, 4) void kconv(const float* __restrict__ x, float* __restrict__ ws) {
    __shared__ __bf16 xt[ZPL*YROWP*XTS_E];             /* 14*23*30*2 = 19320 B */
    int tid = threadIdx.x;
    int bx = blockIdx.x;                               /* 36 = 6z * 3y * 2x */
    int zt = bx / 6;
    int rt = bx % 6; int yt = rt >> 1; int xti = rt & 1;
    int c = blockIdx.y, b = blockIdx.z;
    int z0 = zt*ZSPAN, y0 = yt*YSPAN, x0 = xti*XSPAN;

    const float* xsrc = x + ((size_t)(b*DIM + c))*SP3;
    for (int i = tid; i < ZPL*YROWS*XTS_E; i += 192) { /* 9240 elems */
        int iz = i / (YROWS*XTS_E); int r = i % (YROWS*XTS_E);
        int iy = r / XTS_E; int ix = r % XTS_E;
        int gz = z0 - 3 + iz, gy = y0 - 3 + iy, gx = x0 + ix - 3;
        float v = 0.f;
        if ((unsigned)gz < 48u && (unsigned)gy < 48u && (unsigned)gx < 48u)
            v = xsrc[(gz*SPD + gy)*SPD + gx];
        xt[(iz*YROWP + iy)*XTS_E + ix] = (__bf16)v;
    }
    __syncthreads();

    int tz = tid / 24; int rem = tid % 24; int ty = rem / 3; int tx = rem % 3;
    int xb = tx*8;
    float acc[YB][8];
    #pragma unroll
    for (int yl = 0; yl < YB; ++yl)
        #pragma unroll
        for (int j = 0; j < 8; ++j) acc[yl][j] = 0.f;

    const float4* wp4 = (const float4*)(ws + WS_WDW) + (size_t)(b*DIM + c)*49;

    #pragma unroll 1
    for (int dz = 0; dz < 7; ++dz) {
        float4 wq[7];
        #pragma unroll
        for (int dy = 0; dy < 7; ++dy) wq[dy] = wp4[dz*7 + dy];

        const int zr = (tz + dz)*YROWP + ty*YB;
        #pragma unroll
        for (int r = 0; r < YB + 6; ++r) {
            const uint32_t* rowp = (const uint32_t*)&xt[(zr + r)*XTS_E + xb];
            uint32_t dwv[7];
            #pragma unroll
            for (int k = 0; k < 7; ++k) dwv[k] = rowp[k];
            uint32_t sh[6];
            #pragma unroll
            for (int k = 0; k < 6; ++k)
                asm("v_alignbit_b32 %0, %1, %2, 16"
                    : "=v"(sh[k]) : "v"(dwv[k+1]), "v"(dwv[k]));
            float tlo[4], thi[4];
            #pragma unroll
            for (int m = 0; m < 4; ++m) {
                tlo[m] = __uint_as_float(dwv[3+m] << 16);
                thi[m] = __uint_as_float(dwv[3+m] & 0xffff0000u);
            }
            #pragma unroll
            for (int yl = 0; yl < YB; ++yl) {
                const int dy = r - yl;
                if (dy >= 0 && dy < 7) {
                    const uint32_t w01 = __float_as_uint(wq[dy].x);
                    const uint32_t w23 = __float_as_uint(wq[dy].y);
                    const uint32_t w45 = __float_as_uint(wq[dy].z);
                    const float    w6  = wq[dy].w;
                    #pragma unroll
                    for (int m = 0; m < 4; ++m) {      /* even j = 2m */
                        float a = acc[yl][2*m];
                        DOT2(a, w01, dwv[m]);
                        DOT2(a, w23, dwv[m+1]);
                        DOT2(a, w45, dwv[m+2]);
                        a = fmaf(w6, tlo[m], a);
                        acc[yl][2*m] = a;
                    }
                    #pragma unroll
                    for (int m = 0; m < 4; ++m) {      /* odd j = 2m+1 */
                        float a = acc[yl][2*m+1];
                        DOT2(a, w01, sh[m]);
                        DOT2(a, w23, sh[m+1]);
                        DOT2(a, w45, sh[m+2]);
                        a = fmaf(w6, thi[m], a);
                        acc[yl][2*m+1] = a;
                    }
                }
            }
        }
    }

    float bias = ws[WS_BDW + b*DIM + c];
    #pragma unroll
    for (int yl = 0; yl < YB; ++yl) {
        float* hdst = ws + WS_H + ((size_t)(b*DIM + c))*SP3
                    + (((z0+tz)*SPD + (y0 + ty*YB + yl))*SPD + (x0 + xb));
        #pragma unroll
        for (int j = 0; j < 8; ++j) hdst[j] = acc[yl][j] + bias;
    }
}

/* ---------- kernel 4: LN + pw1 + GELU + pw2 + residual ----------
   R14: register-LN. Lane (j=l16, quad) owns channels c = ks*32+quad*8+t
   — exactly the MFMA B-fragment ownership — so LN reduces across the 4
   quads with two __shfl_xor (16,32) and the Bf fragments materialize in
   VGPRs. Deletes Hn (13.3KB) + redbuf (2KB) + the Phase-A barrier. Only
   the G exchange (intra-wave, cross-quad) uses LDS: per-wave Gq[16][104]
   -> 13312 B total -> ~2x more resident blocks vs R12's 28672. GEMM
   addressing / fragment layouts / chunking byte-identical to R12/R13. */
__global__ __launch_bounds__(256) void kpw(const float* __restrict__ x,
                                           const float* __restrict__ lnw, const float* __restrict__ lnb,
                                           const float* __restrict__ gamma,
                                           float* __restrict__ out, const float* __restrict__ ws) {
    __shared__ __align__(16) __bf16 Gq[4][16][104];   /* 13312 B */

    const int tid  = threadIdx.x;
    const int lane = tid & 63;
    const int w    = tid >> 6;
    const int l16  = lane & 15;
    const int quad = lane >> 4;
    const int b    = blockIdx.y;
    const int sp   = blockIdx.x * 64 + w*16 + l16;   /* this lane's sp column */

    /* ---- Phase A: per-lane h loads + cross-quad LN + B-fragments ---- */
    bf16x8 Bf0, Bf1, Bf2;
    {
        const float* hp = ws + WS_H + (size_t)b*DIM*SP3 + sp;
        float hv[24]; float s = 0.f, qs = 0.f;
        #pragma unroll
        for (int ks = 0; ks < 3; ++ks)
            #pragma unroll
            for (int t = 0; t < 8; ++t) {
                int c = ks*32 + quad*8 + t;
                float v = hp[(size_t)c*SP3];
                hv[ks*8 + t] = v; s += v; qs += v*v;
            }
        s  += __shfl_xor(s, 16, 64);   qs += __shfl_xor(qs, 16, 64);
        s  += __shfl_xor(s, 32, 64);   qs += __shfl_xor(qs, 32, 64);
        float mean = s * (1.f/96.f);
        float var  = qs * (1.f/96.f) - mean*mean;
        float rstd = rsqrtf(fmaxf(var, 0.f) + EPSV);
        #pragma unroll
        for (int t = 0; t < 8; ++t) {
            int c0 = quad*8 + t, c1 = 32 + quad*8 + t, c2 = 64 + quad*8 + t;
            float n0 = (hv[t]      - mean)*rstd*lnw[c0] + lnb[c0];
            float n1 = (hv[8 + t]  - mean)*rstd*lnw[c1] + lnb[c1];
            float n2 = (hv[16 + t] - mean)*rstd*lnw[c2] + lnb[c2];
            Bf0[t] = (__bf16)n0; Bf1[t] = (__bf16)n1; Bf2[t] = (__bf16)n2;
        }
    }

    const __bf16* W1b = (const __bf16*)(ws + WS_W1)  + (size_t)b*C4*DIM;
    const __bf16* W2b = (const __bf16*)(ws + WS_W2T) + (size_t)b*DIM*C4;
    const float*  b1  = ws + WS_B1 + b*C4;
    const float*  b2  = ws + WS_B2 + b*DIM;

    /* GEMM2 accumulators: 6 o-tiles x 4 rows, static-indexed */
    float acc2[6][4];
    #pragma unroll
    for (int m = 0; m < 6; ++m)
        #pragma unroll
        for (int r = 0; r < 4; ++r) acc2[m][r] = 0.f;

    #pragma unroll 1
    for (int q = 0; q < 4; ++q) {
        /* ---- GEMM1 chunk: o = q*96 .. q*96+95 -> gelu -> Gq ---- */
        #pragma unroll 1
        for (int mtl = 0; mtl < 6; ++mtl) {
            const __bf16* ap = W1b + (size_t)((q*6 + mtl)*16 + l16)*DIM + quad*8;
            bf16x8 a0 = *(const bf16x8*)(ap);
            bf16x8 a1 = *(const bf16x8*)(ap + 32);
            bf16x8 a2 = *(const bf16x8*)(ap + 64);
            f32x4 acc = {0.f, 0.f, 0.f, 0.f};
            acc = __builtin_amdgcn_mfma_f32_16x16x32_bf16(a0, Bf0, acc, 0, 0, 0);
            acc = __builtin_amdgcn_mfma_f32_16x16x32_bf16(a1, Bf1, acc, 0, 0, 0);
            acc = __builtin_amdgcn_mfma_f32_16x16x32_bf16(a2, Bf2, acc, 0, 0, 0);
            int og = (q*6 + mtl)*16 + quad*4;   /* global o for bias */
            int ol = mtl*16 + quad*4;           /* local col in Gq */
            bf16x4 gv;
            #pragma unroll
            for (int r = 0; r < 4; ++r) {
                float t = acc[r] + b1[og + r];
                float g = 0.5f*t*(1.f + erff(t*0.70710678f));
                gv[r] = (__bf16)g;
            }
            *(bf16x4*)&Gq[w][l16][ol] = gv;
        }
        __syncthreads();   /* Gq write -> read */

        /* ---- GEMM2 partial: k = q*96 + ksl*32, accumulate acc2 ---- */
        #pragma unroll 1
        for (int ksl = 0; ksl < 3; ++ksl) {
            bf16x8 Bg = *(const bf16x8*)&Gq[w][l16][ksl*32 + quad*8];
            const int kbase = q*96 + ksl*32 + quad*8;
            #pragma unroll
            for (int mt2 = 0; mt2 < 6; ++mt2) {
                const __bf16* ap2 = W2b + (size_t)(mt2*16 + l16)*C4 + kbase;
                bf16x8 a = *(const bf16x8*)(ap2);
                f32x4 cacc = {acc2[mt2][0], acc2[mt2][1], acc2[mt2][2], acc2[mt2][3]};
                cacc = __builtin_amdgcn_mfma_f32_16x16x32_bf16(a, Bg, cacc, 0, 0, 0);
                acc2[mt2][0] = cacc[0]; acc2[mt2][1] = cacc[1];
                acc2[mt2][2] = cacc[2]; acc2[mt2][3] = cacc[3];
            }
        }
        __syncthreads();   /* Gq read done before next chunk overwrites */
    }

    /* ---- epilogue: out = x + gamma*(acc2 + b2) ---- */
    const size_t base = (size_t)b*DIM*SP3 + sp;
    #pragma unroll
    for (int mt2 = 0; mt2 < 6; ++mt2) {
        int obase = mt2*16 + quad*4;
        #pragma unroll
        for (int r = 0; r < 4; ++r) {
            int o = obase + r;
            size_t idx = base + (size_t)o*SP3;
            float y = acc2[mt2][r] + b2[o];
            out[idx] = x[idx] + gamma[o]*y;
        }
    }
}

extern "C" void kernel_launch(void* const* d_in, const int* in_sizes, int n_in,
                              void* d_out, int out_size, void* d_ws, size_t ws_size,
                              hipStream_t stream) {
    const float* x      = (const float*)d_in[0];
    const float* s      = (const float*)d_in[1];
    const float* lnw    = (const float*)d_in[2];
    const float* lnb    = (const float*)d_in[3];
    const float* gamma  = (const float*)d_in[4];
    const float* dwfw   = (const float*)d_in[5];
    const float* dwfb   = (const float*)d_in[6];
    const float* dwbank = (const float*)d_in[7];
    const float* dwbb   = (const float*)d_in[8];
    const float* p1fw   = (const float*)d_in[9];
    const float* p1fb   = (const float*)d_in[10];
    const float* p1bank = (const float*)d_in[11];
    const float* p1bb   = (const float*)d_in[12];
    const float* p2fw   = (const float*)d_in[13];
    const float* p2fb   = (const float*)d_in[14];
    const float* p2bank = (const float*)d_in[15];
    const float* p2bb   = (const float*)d_in[16];
    float* ws  = (float*)d_ws;
    float* out = (float*)d_out;

    kz<<<1, 64, 0, stream>>>(s, dwfw, dwfb, p1fw, p1fb, p2fw, p2fb, ws);
    const int totW = BB*DIM*49*4 + BB*DIM + BB*C4*DIM + BB*C4 + BB*C4*DIM + BB*DIM;
    kw<<<(totW + 255)/256, 256, 0, stream>>>(dwbank, dwbb, p1bank, p1bb, p2bank, p2bb, ws);
    kconv<<<dim3(36, DIM, BB), 192, 0, stream>>>(x, ws);
    kpw<<<dim3(SP3/64, BB), 256, 0, stream>>>(x, lnw, lnb, gamma, out, ws);
}